// Round 4
// baseline (506.926 us; speedup 1.0000x reference)
//
#include <hip/hip_runtime.h>
#include <stdint.h>

#define NUM_NODES 1000000
#define H_DIM 64
#define OUT_DIM 32
#define NUM_RELS 64
#define NUM_BASES 4
#define N_SRC0 400000
#define N_DST1 100000
#define N_DST2 20000
#define E1 600000
#define E2 300000
#define NDST_TOT (N_DST1 + N_DST2)
#define E_TOT (E1 + E2)

typedef __attribute__((ext_vector_type(8))) short bf16x8;
typedef __attribute__((ext_vector_type(4))) float floatx4;

__device__ __forceinline__ unsigned short f2bf(float f){
  union{float f; unsigned u;} v; v.f=f;
  unsigned u=v.u;
  unsigned r=(u + 0x7FFFu + ((u>>16)&1u))>>16;
  return (unsigned short)r;
}
__device__ __forceinline__ float bf2f(unsigned short h){
  union{unsigned u; float f;} v; v.u=((unsigned)h)<<16; return v.f;
}

// ---- init: zero deg[120000] + build B fragment tables ----
__global__ void k_init(const float* __restrict__ V1, const float* __restrict__ V2,
                       ushort* __restrict__ Btab1, ushort* __restrict__ Btab2,
                       int* __restrict__ deg){
  int t = blockIdx.x*blockDim.x + threadIdx.x;
  if (t < NDST_TOT) deg[t] = 0;
  if (t < 16384){
    int j = t & 7, lane = (t>>3)&63, kk = (t>>9)&7, nt = t>>12;     // nt<4
    int kdim = kk*32 + (lane>>4)*8 + j;
    int o = nt*16 + (lane&15);
    int k = kdim>>2, b = kdim&3;
    Btab1[t] = f2bf(V1[(b*64 + k)*64 + o]);
  } else if (t < 24576){
    int u = t - 16384;
    int j = u & 7, lane = (u>>3)&63, kk = (u>>9)&7, nt = u>>12;     // nt<2
    int kdim = kk*32 + (lane>>4)*8 + j;
    int o = nt*16 + (lane&15);
    int k = kdim>>2, b = kdim&3;
    Btab2[u] = f2bf(V2[(b*64 + k)*32 + o]);
  }
}

// ---- histogram over both graphs' dst (graph2 offset by N_DST1) ----
__global__ void k_hist(const int* __restrict__ dst1, const int* __restrict__ dst2,
                       int* __restrict__ deg){
  int t = blockIdx.x*blockDim.x + threadIdx.x;
  if (t < E1) atomicAdd(&deg[dst1[t]], 1);
  else if (t < E_TOT) atomicAdd(&deg[N_DST1 + dst2[t - E1]], 1);
}

// ---- 3-kernel exclusive scan over deg[NDST_TOT] ----
__global__ void k_scan_sum(const int* __restrict__ deg, int* __restrict__ bsum, int n){
  __shared__ int lds[256];
  int tid = threadIdx.x;
  int base = blockIdx.x*1024 + tid*4;
  int s = 0;
  #pragma unroll
  for (int j=0;j<4;j++){ int i = base+j; if (i<n) s += deg[i]; }
  lds[tid] = s; __syncthreads();
  for (int off=128; off>0; off>>=1){ if (tid<off) lds[tid] += lds[tid+off]; __syncthreads(); }
  if (tid==0) bsum[blockIdx.x] = lds[0];
}

__global__ void k_scan_bsum(const int* __restrict__ bsum, int* __restrict__ boff, int nb){
  __shared__ int lds[256];
  int tid = threadIdx.x;
  int v = (tid<nb) ? bsum[tid] : 0;
  lds[tid] = v; __syncthreads();
  for (int off=1; off<256; off<<=1){
    int t = (tid>=off) ? lds[tid-off] : 0; __syncthreads();
    lds[tid] += t; __syncthreads();
  }
  if (tid<nb) boff[tid] = lds[tid] - v;   // exclusive
}

__global__ void k_scan_final(const int* __restrict__ deg, const int* __restrict__ boff,
                             int* __restrict__ offs, int* __restrict__ cursor, int n){
  __shared__ int lds[256];
  int tid = threadIdx.x;
  int base = blockIdx.x*1024 + tid*4;
  int a[4]; int s = 0;
  #pragma unroll
  for (int j=0;j<4;j++){ int i = base+j; a[j] = (i<n)?deg[i]:0; s += a[j]; }
  lds[tid] = s; __syncthreads();
  for (int off=1; off<256; off<<=1){
    int t = (tid>=off) ? lds[tid-off] : 0; __syncthreads();
    lds[tid] += t; __syncthreads();
  }
  int run = boff[blockIdx.x] + (lds[tid] - s);   // global exclusive prefix
  #pragma unroll
  for (int j=0;j<4;j++){
    int i = base+j;
    if (i<n){
      offs[i] = run; cursor[i] = run;
      run += a[j];
      if (i == n-1) offs[n] = run;
    }
  }
}

// ---- scatter both graphs into dst-sorted edge arrays ----
// Layer-1 edges store the RESOLVED emb row (input_nodes[src1[e]]) so agg1
// reads emb directly (no x staging).
__global__ void k_scatter(const int* __restrict__ input_nodes,
                          const int* __restrict__ src1, const int* __restrict__ dst1,
                          const int* __restrict__ ety1, const float* __restrict__ nrm1,
                          const float* __restrict__ comp1,
                          const int* __restrict__ src2, const int* __restrict__ dst2,
                          const int* __restrict__ ety2, const float* __restrict__ nrm2,
                          const float* __restrict__ comp2,
                          int* __restrict__ cursor, int* __restrict__ ssrc,
                          float4* __restrict__ sc){
  int t = blockIdx.x*blockDim.x + threadIdx.x;
  int d, s, et; float nv; const float* comp;
  if (t < E1){
    d = dst1[t]; s = input_nodes[src1[t]]; et = ety1[t]; nv = nrm1[t]; comp = comp1;
  } else if (t < E_TOT){
    int e = t - E1;
    d = N_DST1 + dst2[e]; s = src2[e]; et = ety2[e]; nv = nrm2[e]; comp = comp2;
  } else return;
  int p = atomicAdd(&cursor[d], 1);
  ssrc[p] = s;
  float4 cp = ((const float4*)comp)[et];
  float4 c; c.x = cp.x*nv; c.y = cp.y*nv; c.z = cp.z*nv; c.w = cp.w*nv;
  sc[p] = c;
}

// ---- fused aggregate + GEMM per layer ----
// Block = 1024 threads = 16 waves, 16 dst rows (one row per wave). Edge
// metadata (ssrc/sc) is read with wave-uniform scalar loop index -> compiler
// emits s_load through the scalar cache (no bpermute). Clamped unroll-4 keeps
// 4 source-row loads in flight even in the tail (clamped index is an L1-hot
// repeat with zeroed coefficient). Aggregates stage a 16x256 bf16 tile in
// padded LDS (stride 264 -> 2-way bank aliasing only, free), then waves 0..3
// (resp 0..1) compute the MFMA n-tiles.

__global__ __launch_bounds__(1024) void k_agg_gemm1(
    const float* __restrict__ emb, const int* __restrict__ offs,
    const int* __restrict__ ssrc, const float4* __restrict__ sc,
    const ushort* __restrict__ Btab, const float* __restrict__ bias,
    ushort* __restrict__ h_bf){
  __shared__ ushort zt[16][264];
  int lane = threadIdx.x & 63;
  int w = threadIdx.x >> 6;              // 0..15
  int mbase = blockIdx.x * 16;
  int d = mbase + w;
  int e0 = offs[d], e1 = offs[d+1];
  float a0=0.f, a1=0.f, a2=0.f, a3=0.f;
  int elast = e1 - 1;
  for (int e = e0; e < e1; e += 4){
    int i0 = e,            i1 = min(e+1, elast);
    int i2 = min(e+2, elast), i3 = min(e+3, elast);
    int s0 = ssrc[i0], s1 = ssrc[i1], s2 = ssrc[i2], s3 = ssrc[i3];
    float4 c0 = sc[i0], c1 = sc[i1], c2 = sc[i2], c3 = sc[i3];
    if (e+1 > elast){ c1.x=0.f;c1.y=0.f;c1.z=0.f;c1.w=0.f; }
    if (e+2 > elast){ c2.x=0.f;c2.y=0.f;c2.z=0.f;c2.w=0.f; }
    if (e+3 > elast){ c3.x=0.f;c3.y=0.f;c3.z=0.f;c3.w=0.f; }
    float x0 = emb[(size_t)s0*64 + lane];
    float x1 = emb[(size_t)s1*64 + lane];
    float x2 = emb[(size_t)s2*64 + lane];
    float x3 = emb[(size_t)s3*64 + lane];
    a0 = fmaf(c0.x, x0, a0); a1 = fmaf(c0.y, x0, a1);
    a2 = fmaf(c0.z, x0, a2); a3 = fmaf(c0.w, x0, a3);
    a0 = fmaf(c1.x, x1, a0); a1 = fmaf(c1.y, x1, a1);
    a2 = fmaf(c1.z, x1, a2); a3 = fmaf(c1.w, x1, a3);
    a0 = fmaf(c2.x, x2, a0); a1 = fmaf(c2.y, x2, a1);
    a2 = fmaf(c2.z, x2, a2); a3 = fmaf(c2.w, x2, a3);
    a0 = fmaf(c3.x, x3, a0); a1 = fmaf(c3.y, x3, a1);
    a2 = fmaf(c3.z, x3, a2); a3 = fmaf(c3.w, x3, a3);
  }
  ushort4 o; o.x=f2bf(a0); o.y=f2bf(a1); o.z=f2bf(a2); o.w=f2bf(a3);
  *(ushort4*)&zt[w][lane*4] = o;
  __syncthreads();
  if (w >= 4) return;                    // N=64 -> 4 n-tiles
  int quad = lane>>4, l15 = lane&15;
  bf16x8 a[8];
  #pragma unroll
  for (int kk=0; kk<8; kk++)
    a[kk] = *(const bf16x8*)&zt[l15][kk*32 + quad*8];
  floatx4 acc = {0.f,0.f,0.f,0.f};
  #pragma unroll
  for (int kk=0; kk<8; kk++){
    bf16x8 b = *((const bf16x8*)(Btab + ((w*8 + kk)*64 + lane)*8));
    acc = __builtin_amdgcn_mfma_f32_16x16x32_bf16(a[kk], b, acc, 0, 0, 0);
  }
  int col = w*16 + l15;
  float bv = bias[col];
  #pragma unroll
  for (int r=0; r<4; r++){
    int row = mbase + quad*4 + r;
    float v = fmaxf(acc[r] + bv, 0.f);
    h_bf[(size_t)row*64 + col] = f2bf(v);
  }
}

__global__ __launch_bounds__(1024) void k_agg_gemm2(
    const ushort* __restrict__ hin, const int* __restrict__ offs,
    const int* __restrict__ ssrc, const float4* __restrict__ sc,
    const ushort* __restrict__ Btab, const float* __restrict__ bias,
    float* __restrict__ out){
  __shared__ ushort zt[16][264];
  int lane = threadIdx.x & 63;
  int w = threadIdx.x >> 6;
  int mbase = blockIdx.x * 16;
  int d = mbase + w;
  int e0 = offs[d], e1 = offs[d+1];
  float a0=0.f, a1=0.f, a2=0.f, a3=0.f;
  int elast = e1 - 1;
  for (int e = e0; e < e1; e += 4){
    int i0 = e,            i1 = min(e+1, elast);
    int i2 = min(e+2, elast), i3 = min(e+3, elast);
    int s0 = ssrc[i0], s1 = ssrc[i1], s2 = ssrc[i2], s3 = ssrc[i3];
    float4 c0 = sc[i0], c1 = sc[i1], c2 = sc[i2], c3 = sc[i3];
    if (e+1 > elast){ c1.x=0.f;c1.y=0.f;c1.z=0.f;c1.w=0.f; }
    if (e+2 > elast){ c2.x=0.f;c2.y=0.f;c2.z=0.f;c2.w=0.f; }
    if (e+3 > elast){ c3.x=0.f;c3.y=0.f;c3.z=0.f;c3.w=0.f; }
    float x0 = bf2f(hin[(size_t)s0*64 + lane]);
    float x1 = bf2f(hin[(size_t)s1*64 + lane]);
    float x2 = bf2f(hin[(size_t)s2*64 + lane]);
    float x3 = bf2f(hin[(size_t)s3*64 + lane]);
    a0 = fmaf(c0.x, x0, a0); a1 = fmaf(c0.y, x0, a1);
    a2 = fmaf(c0.z, x0, a2); a3 = fmaf(c0.w, x0, a3);
    a0 = fmaf(c1.x, x1, a0); a1 = fmaf(c1.y, x1, a1);
    a2 = fmaf(c1.z, x1, a2); a3 = fmaf(c1.w, x1, a3);
    a0 = fmaf(c2.x, x2, a0); a1 = fmaf(c2.y, x2, a1);
    a2 = fmaf(c2.z, x2, a2); a3 = fmaf(c2.w, x2, a3);
    a0 = fmaf(c3.x, x3, a0); a1 = fmaf(c3.y, x3, a1);
    a2 = fmaf(c3.z, x3, a2); a3 = fmaf(c3.w, x3, a3);
  }
  ushort4 o; o.x=f2bf(a0); o.y=f2bf(a1); o.z=f2bf(a2); o.w=f2bf(a3);
  *(ushort4*)&zt[w][lane*4] = o;
  __syncthreads();
  if (w >= 2) return;                    // N=32 -> 2 n-tiles
  int quad = lane>>4, l15 = lane&15;
  bf16x8 a[8];
  #pragma unroll
  for (int kk=0; kk<8; kk++)
    a[kk] = *(const bf16x8*)&zt[l15][kk*32 + quad*8];
  floatx4 acc = {0.f,0.f,0.f,0.f};
  #pragma unroll
  for (int kk=0; kk<8; kk++){
    bf16x8 b = *((const bf16x8*)(Btab + ((w*8 + kk)*64 + lane)*8));
    acc = __builtin_amdgcn_mfma_f32_16x16x32_bf16(a[kk], b, acc, 0, 0, 0);
  }
  int col = w*16 + l15;
  float bv = bias[col];
  #pragma unroll
  for (int r=0; r<4; r++){
    int row = mbase + quad*4 + r;
    out[(size_t)row*32 + col] = acc[r] + bv;
  }
}

extern "C" void kernel_launch(void* const* d_in, const int* in_sizes, int n_in,
                              void* d_out, int out_size, void* d_ws, size_t ws_size,
                              hipStream_t stream){
  const int*   input_nodes = (const int*)  d_in[0];
  const int*   src1  = (const int*)  d_in[1];
  const int*   dst1  = (const int*)  d_in[2];
  const int*   ety1  = (const int*)  d_in[3];
  const float* norm1 = (const float*)d_in[4];
  const int*   src2  = (const int*)  d_in[5];
  const int*   dst2  = (const int*)  d_in[6];
  const int*   ety2  = (const int*)  d_in[7];
  const float* norm2 = (const float*)d_in[8];
  const float* emb   = (const float*)d_in[9];
  const float* V1    = (const float*)d_in[10];
  const float* comp1 = (const float*)d_in[11];
  const float* b1    = (const float*)d_in[12];
  const float* V2    = (const float*)d_in[13];
  const float* comp2 = (const float*)d_in[14];
  const float* b2    = (const float*)d_in[15];
  float* out = (float*)d_out;

  char* p = (char*)d_ws;
  auto alloc = [&](size_t bytes)->char*{
    char* r = p; p += (bytes + 255) & ~(size_t)255; return r;
  };
  ushort* h_bf  = (ushort*)alloc((size_t)N_DST1*64*2);     // 12.8 MB
  ushort* Btab1 = (ushort*)alloc(16384*2);
  ushort* Btab2 = (ushort*)alloc(8192*2);
  int* deg  = (int*)alloc((size_t)NDST_TOT*4);
  int* cur  = (int*)alloc((size_t)NDST_TOT*4);
  int* offs = (int*)alloc((size_t)(NDST_TOT+1)*4);
  int* bs   = (int*)alloc(256*4);
  int* bo   = (int*)alloc(256*4);
  int* ssrc = (int*)alloc((size_t)E_TOT*4);
  float4* sc = (float4*)alloc((size_t)E_TOT*16);

  // 1. init (deg zero + B tables)
  k_init<<<(NDST_TOT + 255)/256, 256, 0, stream>>>(V1, V2, Btab1, Btab2, deg);
  // 2-5. CSR build (both graphs batched)
  k_hist<<<(E_TOT + 255)/256, 256, 0, stream>>>(dst1, dst2, deg);
  int nb = (NDST_TOT + 1023)/1024;   // 118
  k_scan_sum<<<nb, 256, 0, stream>>>(deg, bs, NDST_TOT);
  k_scan_bsum<<<1, 256, 0, stream>>>(bs, bo, nb);
  k_scan_final<<<nb, 256, 0, stream>>>(deg, bo, offs, cur, NDST_TOT);
  // 6. scatter both graphs (resolves input_nodes for layer 1)
  k_scatter<<<(E_TOT + 255)/256, 256, 0, stream>>>(input_nodes,
                                                   src1, dst1, ety1, norm1, comp1,
                                                   src2, dst2, ety2, norm2, comp2,
                                                   cur, ssrc, sc);
  // 7. layer 1 fused agg(direct emb)+gemm (+relu)
  k_agg_gemm1<<<N_DST1/16, 1024, 0, stream>>>(emb, offs, ssrc, sc, Btab1, b1, h_bf);
  // 8. layer 2 fused agg+gemm -> out
  k_agg_gemm2<<<N_DST2/16, 1024, 0, stream>>>(h_bf, offs + N_DST1, ssrc, sc, Btab2, b2, out);

  (void)in_sizes; (void)n_in; (void)out_size; (void)ws_size;
}